// Round 12
// baseline (622.255 us; speedup 1.0000x reference)
//
#include <hip/hip_runtime.h>
#include <hip/hip_bf16.h>
#include <math.h>

typedef __hip_bfloat16 bf16;
typedef __bf16 bf16x8 __attribute__((ext_vector_type(8)));
typedef float f32x4 __attribute__((ext_vector_type(4)));
typedef unsigned short u16;
typedef u16 u16x8 __attribute__((ext_vector_type(8)));

#define NB 4096          // batch rows
#define DM 768           // model dim

__device__ __forceinline__ float cvt(float x){ return x; }
__device__ __forceinline__ float cvt(bf16 x){ return __bfloat162float(x); }
__device__ __forceinline__ void stv(float* p, float v){ *p = v; }
__device__ __forceinline__ void stv(bf16* p, float v){ *p = __float2bfloat16(v); }

__device__ __forceinline__ float gelu_f(float x){
    return 0.5f * x * (1.0f + erff(x * 0.70710678118654752440f));
}
__device__ __forceinline__ float sigmoid_f(float x){
    return 1.0f / (1.0f + __expf(-x));
}

__device__ __forceinline__ void async_copy16(const void* g, void* l){
    __builtin_amdgcn_global_load_lds((const __attribute__((address_space(1))) void*)g,
                                     (__attribute__((address_space(3))) void*)l, 16, 0, 0);
}

// ---------------------------------------------------------------------------
// Flat multi-job MFMA GEMM (R7 K-loop/epilogue structure -- proven optimum;
// R8's 32KB two-pass epilogue REGRESSED; R10's atomic rowsum REGRESSED).
// Per job: C = act((A @ Bm^T + b0) * alpha * gv + b1)
// act: 0 none, 1 gelu, 2 sigmoid, 3 relu, 4 exp (__expf; scores tiny -> no max).
// rs: per-block partial row sums -> rs[gx*M+row] (exactly-once, no atomics).
// sw: 8x8 supertile block swizzle (L2 locality; requires nx%8==0, ny%8==0).
// cp: cls-fusion mode -- no C store; v=sig((acc+b0)*alpha); partial logits
//     part[gx][row][3] from v * ca[row,col] * cs[col] . cw[class,col].
// A: (M,ldA) bf16 cols [0,K). Bm: (N,ldB) bf16 (B^T layout) cols [0,K).
// M%128==0, N%128==0, K%64==0. trans=1: store C^T into (N,M).
// ---------------------------------------------------------------------------
#define MAXJ 8
struct Job {
    const bf16* A; const bf16* B; bf16* C;
    const float* b0; const float* gv; const float* b1;
    float* rs;
    const bf16* ca; const float* cs; const float* cw; float* cp;
    int M, N, K, ldA, ldB, act, trans, blk0, nx, sw;
    float alpha;
};
struct Jobs { Job j[MAXJ]; int nj; };

__global__ __launch_bounds__(256) void mgemm_k(Jobs jb)
{
    int z = 0;
    #pragma unroll
    for (int i = 1; i < MAXJ; ++i)
        if (i < jb.nj && (int)blockIdx.x >= jb.j[i].blk0) z = i;
    const Job& J = jb.j[z];
    const bf16* __restrict__ A  = J.A;
    const bf16* __restrict__ Bm = J.B;
    bf16* __restrict__ C        = J.C;
    const int bx = (int)blockIdx.x - J.blk0;
    int gx, gy;
    if (J.sw){
        const int st = bx >> 6, in = bx & 63;
        const int nsx = J.nx >> 3;
        gx = (st % nsx) * 8 + (in & 7);
        gy = (st / nsx) * 8 + (in >> 3);
    } else { gx = bx % J.nx; gy = bx / J.nx; }
    const int M = J.M, N = J.N, K = J.K, ldA = J.ldA, ldB = J.ldB;

    // staging: A = smem[0 .. 8191] (128x64), B = smem[8192 .. 16383]
    // epilogue: 128x136 bf16 tile = 17408 elems
    __shared__ __align__(16) bf16 smem[17408];
    const int tid  = threadIdx.x;
    const int wave = tid >> 6;
    const int lane = tid & 63;
    const int row0 = gy * 128;
    const int col0 = gx * 128;
    const int wrow = (wave & 1) * 64;
    const int wcol = (wave >> 1) * 64;
    const int fl   = lane & 15;
    const int q    = lane >> 4;

    // staging: per instr a wave stages 8 rows x 64 cols (1 KiB).
    // phys chunk (lane&7) at row r holds logical chunk (lane&7)^(r&7).
    const int sr8 = lane >> 3;
    const int sc8 = (((lane & 7) ^ sr8)) * 8;
    const bf16* pA = A  + (size_t)(row0 + wave * 32 + sr8) * ldA + sc8;
    const bf16* pB = Bm + (size_t)(col0 + wave * 32 + sr8) * ldB + sc8;
    bf16* ldsA = &smem[(wave * 32) * 64];
    bf16* ldsB = &smem[8192 + (wave * 32) * 64];

    f32x4 acc[4][4] = {};
    for (int k0 = 0; k0 < K; k0 += 64){
        #pragma unroll
        for (int i = 0; i < 4; ++i){
            async_copy16(pA + (size_t)(i * 8) * ldA, ldsA + i * 512);
            async_copy16(pB + (size_t)(i * 8) * ldB, ldsB + i * 512);
        }
        pA += 64; pB += 64;
        __syncthreads();
        #pragma unroll
        for (int ks = 0; ks < 2; ++ks){
            bf16x8 af[4], bfv[4];
            #pragma unroll
            for (int i = 0; i < 4; ++i){
                const int ra = wrow + i * 16 + fl;
                const int rb = wcol + i * 16 + fl;
                const int ca2 = ((ks * 4 + q) ^ (ra & 7)) * 8;
                const int cb2 = ((ks * 4 + q) ^ (rb & 7)) * 8;
                af[i]  = *(const bf16x8*)&smem[ra * 64 + ca2];
                bfv[i] = *(const bf16x8*)&smem[8192 + rb * 64 + cb2];
            }
            #pragma unroll
            for (int mi = 0; mi < 4; ++mi)
                #pragma unroll
                for (int ni = 0; ni < 4; ++ni)
                    acc[mi][ni] = __builtin_amdgcn_mfma_f32_16x16x32_bf16(af[mi], bfv[ni], acc[mi][ni], 0, 0, 0);
        }
        __syncthreads();
    }

    if (J.cp == nullptr){
        // standard epilogue: C/D layout col = lane&15, row = q*4 + reg.
        // stage to LDS (padded ld=136), block-wide 256 B coalesced stores.
        constexpr int ELD = 136;
        #pragma unroll
        for (int ni = 0; ni < 4; ++ni){
            const int col = col0 + wcol + ni * 16 + fl;
            const float b0 = J.b0 ? J.b0[col] : 0.f;
            const float gm = (J.gv ? J.gv[col] : 1.f) * J.alpha;
            const float b1 = J.b1 ? J.b1[col] : 0.f;
            const int lcol = wcol + ni * 16 + fl;
            #pragma unroll
            for (int mi = 0; mi < 4; ++mi){
                const int lrow = wrow + mi * 16 + q * 4;
                #pragma unroll
                for (int r = 0; r < 4; ++r){
                    float v = (acc[mi][ni][r] + b0) * gm + b1;
                    if      (J.act == 1) v = gelu_f(v);
                    else if (J.act == 2) v = sigmoid_f(v);
                    else if (J.act == 3) v = fmaxf(v, 0.f);
                    else if (J.act == 4) v = __expf(v);
                    if (J.trans) smem[(size_t)lcol * ELD + lrow + r] = __float2bfloat16(v);
                    else         smem[(size_t)(lrow + r) * ELD + lcol] = __float2bfloat16(v);
                }
            }
        }
        __syncthreads();
        const int erow = tid >> 4;
        const int ecol = (tid & 15) * 8;
        #pragma unroll
        for (int p = 0; p < 8; ++p){
            const int row = p * 16 + erow;
            const u16x8 uv = *(const u16x8*)&smem[row * ELD + ecol];
            if (J.trans) *(u16x8*)&C[(size_t)(col0 + row) * M + row0 + ecol] = uv;
            else         *(u16x8*)&C[(size_t)(row0 + row) * N + col0 + ecol] = uv;
            if (J.rs){
                float s = 0.f;
                #pragma unroll
                for (int j = 0; j < 8; ++j) s += __uint_as_float((unsigned)uv[j] << 16);
                s += __shfl_down(s, 8, 16);
                s += __shfl_down(s, 4, 16);
                s += __shfl_down(s, 2, 16);
                s += __shfl_down(s, 1, 16);
                if ((tid & 15) == 0) J.rs[(size_t)gx * M + row0 + row] = s;
            }
        }
    } else {
        // cls-fusion epilogue: partial logits, no C store.
        // sp[colhalf][128 rows][3]; each slot written by exactly one lane.
        float* sp = (float*)smem;
        const int colhalf = wave >> 1;
        #pragma unroll
        for (int mi = 0; mi < 4; ++mi){
            #pragma unroll
            for (int r = 0; r < 4; ++r){
                const int lrow = wrow + mi * 16 + q * 4 + r;
                const int grow = row0 + lrow;
                float s0 = 0.f, s1 = 0.f, s2 = 0.f;
                #pragma unroll
                for (int ni = 0; ni < 4; ++ni){
                    const int col = col0 + wcol + ni * 16 + fl;
                    const float b0 = J.b0 ? J.b0[col] : 0.f;
                    float v = sigmoid_f((acc[mi][ni][r] + b0) * J.alpha);
                    const float t = v * cvt(J.ca[(size_t)grow * DM + col]) * J.cs[col];
                    s0 = fmaf(t, J.cw[col],          s0);
                    s1 = fmaf(t, J.cw[DM + col],     s1);
                    s2 = fmaf(t, J.cw[2 * DM + col], s2);
                }
                #pragma unroll
                for (int m2 = 1; m2 < 16; m2 <<= 1){
                    s0 += __shfl_xor(s0, m2, 64);
                    s1 += __shfl_xor(s1, m2, 64);
                    s2 += __shfl_xor(s2, m2, 64);
                }
                if (fl == 0){
                    sp[colhalf * 384 + lrow * 3 + 0] = s0;
                    sp[colhalf * 384 + lrow * 3 + 1] = s1;
                    sp[colhalf * 384 + lrow * 3 + 2] = s2;
                }
            }
        }
        __syncthreads();
        if (tid < 128){
            float* dst = J.cp + ((size_t)gx * NB + row0 + tid) * 3;
            dst[0] = sp[tid * 3 + 0] + sp[384 + tid * 3 + 0];
            dst[1] = sp[tid * 3 + 1] + sp[384 + tid * 3 + 1];
            dst[2] = sp[tid * 3 + 2] + sp[384 + tid * 3 + 2];
        }
    }
}

// Final: logits[row] = sum over 2 dirs x 6 col-chunks of partials + bias; softmax(3)
__global__ __launch_bounds__(256) void cls_final_k(
    const float* __restrict__ part, const float* __restrict__ bias, float* __restrict__ out)
{
    const int row = blockIdx.x * 256 + threadIdx.x;
    if (row >= NB) return;
    float l0 = bias[0], l1 = bias[1], l2 = bias[2];
    #pragma unroll
    for (int s = 0; s < 12; ++s){
        const float* p = part + ((size_t)s * NB + row) * 3;
        l0 += p[0]; l1 += p[1]; l2 += p[2];
    }
    const float mx = fmaxf(l0, fmaxf(l1, l2));
    const float e0 = __expf(l0 - mx), e1 = __expf(l1 - mx), e2 = __expf(l2 - mx);
    const float inv = 1.f / (e0 + e1 + e2);
    out[(size_t)row * 3 + 0] = e0 * inv;
    out[(size_t)row * 3 + 1] = e1 * inv;
    out[(size_t)row * 3 + 2] = e2 * inv;
}

// Reduce 32 per-chunk partials per row into the softmax denominator.
__global__ __launch_bounds__(256) void denom_k(const float* __restrict__ part, float* __restrict__ l)
{
    const int t = blockIdx.x * 256 + threadIdx.x;
    if (t >= 2 * NB) return;
    const int dir = t >> 12, row = t & (NB - 1);
    const float* p = part + (size_t)dir * 32 * NB + row;
    float s = 0.f;
    #pragma unroll
    for (int c = 0; c < 32; ++c) s += p[(size_t)c * NB];
    l[t] = s;
}

// Batched fp32 -> bf16 conversion; last y-slice does the conv center-tap extraction
#define NCVT 14
struct CvtDesc {
    const float* s[NCVT]; bf16* d[NCVT]; int n[NCVT];
    const float* w1; const float* saw; bf16* w1c; float* sac;
};
__global__ __launch_bounds__(256) void cvt_k(CvtDesc cd)
{
    const int e = blockIdx.y;
    if (e == NCVT){
        const int idx = blockIdx.x * 256 + threadIdx.x;
        if (idx < 384 * 768){
            const int oc = idx / 768, ic = idx % 768;
            cd.w1c[idx] = __float2bfloat16(cd.w1[(size_t)oc * 6912 + (size_t)ic * 9 + 4]);
        }
        if (idx < 384) cd.sac[idx] = cd.saw[(size_t)idx * 49 + 24];
        return;
    }
    const int base = (blockIdx.x * 256 + threadIdx.x) * 4;
    if (base >= cd.n[e]) return;
    const float4 v = *(const float4*)(cd.s[e] + base);
    union { bf16 h[4]; unsigned long long u; } o;
    o.h[0] = __float2bfloat16(v.x);
    o.h[1] = __float2bfloat16(v.y);
    o.h[2] = __float2bfloat16(v.z);
    o.h[3] = __float2bfloat16(v.w);
    *(unsigned long long*)(cd.d[e] + base) = o.u;
}

// Fused FDA tail: ca1 -> ca2 -> x2 -> sa -> x3 -> dec -> x4, in place
__global__ __launch_bounds__(128) void fda_fused_k(
    bf16* __restrict__ x, const float* __restrict__ wc1, const float* __restrict__ wc2,
    const float* __restrict__ sac, const float* __restrict__ sab,
    const float* __restrict__ decw, const float* __restrict__ decb,
    const float* __restrict__ sigma)
{
    __shared__ float xs[384];
    __shared__ float ca1s[24];
    __shared__ float red[128];
    const int b = blockIdx.x;
    const int tid = threadIdx.x;
    bf16* xr = x + (size_t)b * 384;
    #pragma unroll
    for (int i = 0; i < 3; ++i) xs[tid + i * 128] = cvt(xr[tid + i * 128]);
    __syncthreads();
    if (tid < 96){
        const int o = tid >> 2, sub = tid & 3;
        const float* w = wc1 + (size_t)o * 384 + sub * 96;
        float p = 0.f;
        #pragma unroll 8
        for (int k = 0; k < 96; ++k) p = fmaf(xs[sub * 96 + k], w[k], p);
        p += __shfl_down(p, 1, 64);
        p += __shfl_down(p, 2, 64);
        if (sub == 0) ca1s[o] = gelu_f(p);
    }
    __syncthreads();
    float x2[3];
    float p = 0.f;
    #pragma unroll
    for (int i = 0; i < 3; ++i){
        const int c = tid + i * 128;
        float s = 0.f;
        const float* w = wc2 + (size_t)c * 24;
        #pragma unroll
        for (int k = 0; k < 24; ++k) s = fmaf(ca1s[k], w[k], s);
        const float v = xs[c] * sigmoid_f(s);
        x2[i] = v;
        p += v * sac[c];
    }
    red[tid] = p; __syncthreads();
    for (int s = 64; s > 0; s >>= 1){ if (tid < s) red[tid] += red[tid + s]; __syncthreads(); }
    const float sa = sigmoid_f(red[0] + sab[0]);
    __syncthreads();
    float qq = 0.f;
    #pragma unroll
    for (int i = 0; i < 3; ++i){
        const int c = tid + i * 128;
        x2[i] *= sa;
        qq += x2[i] * decw[c];
    }
    red[tid] = qq; __syncthreads();
    for (int s = 64; s > 0; s >>= 1){ if (tid < s) red[tid] += red[tid + s]; __syncthreads(); }
    const float xg = gelu_f(red[0] + decb[0]);
    #pragma unroll
    for (int i = 0; i < 3; ++i){
        const int c = tid + i * 128;
        const float sg = sigma[c];
        stv(&xr[c], x2[i] + sg * (x2[i] - xg));
    }
}

// o1 = (a+b)/l1[row] ; o2 = (c+d)/l2[row]  (split-K reduce + softmax denom)
__global__ __launch_bounds__(256) void reduce2_k(
    const bf16* __restrict__ a, const bf16* __restrict__ b, bf16* __restrict__ o1,
    const float* __restrict__ l1,
    const bf16* __restrict__ c, const bf16* __restrict__ d, bf16* __restrict__ o2,
    const float* __restrict__ l2)
{
    const size_t i = ((size_t)blockIdx.x * 256 + threadIdx.x) * 8;
    if (i >= (size_t)NB * DM) return;
    const int row = (int)(i / DM);
    const float inv1 = 1.0f / l1[row];
    const float inv2 = 1.0f / l2[row];
    u16x8 ua = *(const u16x8*)((const u16*)a + i);
    u16x8 ub = *(const u16x8*)((const u16*)b + i);
    u16x8 uc = *(const u16x8*)((const u16*)c + i);
    u16x8 ud = *(const u16x8*)((const u16*)d + i);
    u16x8 r1, r2;
    #pragma unroll
    for (int j = 0; j < 8; ++j){
        const float s1 = (__uint_as_float((unsigned)ua[j] << 16) + __uint_as_float((unsigned)ub[j] << 16)) * inv1;
        const float s2 = (__uint_as_float((unsigned)uc[j] << 16) + __uint_as_float((unsigned)ud[j] << 16)) * inv2;
        r1[j] = __bfloat16_as_ushort(__float2bfloat16(s1));
        r2[j] = __bfloat16_as_ushort(__float2bfloat16(s2));
    }
    *(u16x8*)((u16*)o1 + i) = r1;
    *(u16x8*)((u16*)o2 + i) = r2;
}

extern "C" void kernel_launch(void* const* d_in, const int* in_sizes, int n_in,
                              void* d_out, int out_size, void* d_ws, size_t ws_size,
                              hipStream_t stream)
{
    const float* text   = (const float*)d_in[0];
    const float* image  = (const float*)d_in[1];
    const float* tl_w   = (const float*)d_in[2];
    const float* tl_b   = (const float*)d_in[3];
    const float* il_w   = (const float*)d_in[4];
    const float* il_b   = (const float*)d_in[5];
    const float* sda_wv = (const float*)d_in[10];
    const float* sda_bv = (const float*)d_in[11];
    const float* sda_wo = (const float*)d_in[12];
    const float* sda_bo = (const float*)d_in[13];
    const float* fda_w1 = (const float*)d_in[14];
    const float* fda_b1 = (const float*)d_in[15];
    const float* bn1_g  = (const float*)d_in[16];
    const float* bn1_b  = (const float*)d_in[17];
    const float* ca_w1  = (const float*)d_in[18];
    const float* ca_w2  = (const float*)d_in[19];
    const float* sa_w   = (const float*)d_in[20];
    const float* sa_b   = (const float*)d_in[21];
    const float* dec_w  = (const float*)d_in[22];
    const float* dec_b  = (const float*)d_in[23];
    const float* sigma  = (const float*)d_in[24];
    const float* fda_wf = (const float*)d_in[25];
    const float* fda_bf = (const float*)d_in[26];
    const float* bn2_g  = (const float*)d_in[27];
    const float* bn2_b  = (const float*)d_in[28];
    const float* dmi_wq = (const float*)d_in[29];
    const float* dmi_bq = (const float*)d_in[30];
    const float* dmi_wk = (const float*)d_in[31];
    const float* dmi_bk = (const float*)d_in[32];
    const float* dmi_wv = (const float*)d_in[33];
    const float* dmi_bv = (const float*)d_in[34];
    const float* tg_w1  = (const float*)d_in[35];
    const float* tg_b1  = (const float*)d_in[36];
    const float* tg_w2  = (const float*)d_in[37];
    const float* tg_b2  = (const float*)d_in[38];
    const float* ig_w1  = (const float*)d_in[39];
    const float* ig_b1  = (const float*)d_in[40];
    const float* ig_w2  = (const float*)d_in[41];
    const float* ig_b2  = (const float*)d_in[42];
    const float* t_scale= (const float*)d_in[43];
    const float* i_scale= (const float*)d_in[44];
    const float* cls_w  = (const float*)d_in[45];
    const float* cls_b  = (const float*)d_in[46];
    float* out = (float*)d_out;

    // ---- workspace (~130 MB) ----
    char* base = (char*)d_ws;
    auto alloc = [&](size_t bytes){ void* p = (void*)base; base += (bytes + 255) & ~(size_t)255; return p; };
    const size_t SLOT = (size_t)NB * DM;
    const size_t W768 = (size_t)768 * 768;
    bf16* tl_wb   = (bf16*)alloc(W768 * 2);
    bf16* il_wb   = (bf16*)alloc(W768 * 2);
    bf16* sda_wvb = (bf16*)alloc((size_t)512 * 768 * 2);
    bf16* sda_wob = (bf16*)alloc((size_t)768 * 512 * 2);
    bf16* fda_wfb = (bf16*)alloc((size_t)768 * 384 * 2);
    bf16* dmi_wqb = (bf16*)alloc(W768 * 2);
    bf16* dmi_wkb = (bf16*)alloc(W768 * 2);
    bf16* dmi_wvb = (bf16*)alloc(W768 * 2);
    bf16* tg_w1b  = (bf16*)alloc(W768 * 2);
    bf16* tg_w2b  = (bf16*)alloc(W768 * 2);
    bf16* ig_w1b  = (bf16*)alloc(W768 * 2);
    bf16* ig_w2b  = (bf16*)alloc(W768 * 2);
    bf16* w1c     = (bf16*)alloc((size_t)384 * 768 * 2);
    float* sac    = (float*)alloc(1536 * 4);
    float* lbuf   = (float*)alloc(2 * NB * 4);               // softmax denominators [2][NB]
    float* part   = (float*)alloc((size_t)2 * 32 * NB * 4);  // score rowsum partials, 1 MB
    float* clsp   = (float*)alloc((size_t)2 * 6 * NB * 3 * 4); // cls logit partials, 590 KB
    bf16* SL[8];
    for (int i = 0; i < 8; ++i) SL[i] = (bf16*)alloc(SLOT * 2);
    bf16* SC1 = (bf16*)alloc((size_t)NB * NB * 2);
    bf16* SC2 = (bf16*)alloc((size_t)NB * NB * 2);

    const float bnscale = 1.0f / sqrtf(1.0f + 1e-5f);
    const float iscale  = 1.0f / sqrtf(768.0f);
    const dim3 blk(256);

    struct JB {
        Jobs jb; int blocks;
        Job& add(const bf16* A, const bf16* B, bf16* C, int M, int N, int K, int ldA, int ldB,
                 const float* b0, float al, const float* gv, const float* b1, int act, int trans,
                 float* rs = nullptr){
            Job& j = jb.j[jb.nj++];
            j = Job{};
            j.A=A; j.B=B; j.C=C; j.b0=b0; j.gv=gv; j.b1=b1; j.rs=rs;
            j.M=M; j.N=N; j.K=K; j.ldA=ldA; j.ldB=ldB; j.act=act; j.trans=trans;
            j.alpha=al; j.blk0=blocks; j.nx=N/128; j.sw=0;
            blocks += (N/128)*(M/128);
            return j;
        }
    };
    auto launch = [&](JB& b){ mgemm_k<<<dim3(b.blocks), blk, 0, stream>>>(b.jb); };

    // fp32 -> bf16 staging (+ fused center-tap extraction in y-slice NCVT)
    CvtDesc cd;
    const float* srcs[NCVT] = {text, image, tl_w, il_w, sda_wv, sda_wo, fda_wf,
                               dmi_wq, dmi_wk, dmi_wv, tg_w1, tg_w2, ig_w1, ig_w2};
    bf16* dsts[NCVT] = {SL[0], SL[1], tl_wb, il_wb, sda_wvb, sda_wob, fda_wfb,
                        dmi_wqb, dmi_wkb, dmi_wvb, tg_w1b, tg_w2b, ig_w1b, ig_w2b};
    int   lens[NCVT] = {(int)SLOT, (int)SLOT, (int)W768, (int)W768, 512*768, 768*512, 768*384,
                        (int)W768, (int)W768, (int)W768, (int)W768, (int)W768, (int)W768, (int)W768};
    for (int i = 0; i < NCVT; ++i){ cd.s[i] = srcs[i]; cd.d[i] = dsts[i]; cd.n[i] = lens[i]; }
    cd.w1 = fda_w1; cd.saw = sa_w; cd.w1c = w1c; cd.sac = sac;
    cvt_k<<<dim3((int)(SLOT / 1024), NCVT + 1), blk, 0, stream>>>(cd);

    // J1: t0 = gelu(text@tl^T) -> SL2 ; im0 = gelu(image@il^T) -> SL3
    { JB b{}; b.add(SL[0], tl_wb, SL[2], NB, DM, DM, DM, DM, tl_b, 1.f, nullptr, nullptr, 1, 0);
              b.add(SL[1], il_wb, SL[3], NB, DM, DM, DM, DM, il_b, 1.f, nullptr, nullptr, 1, 0); launch(b); }
    // J2: wv = t0@wv^T -> SL0 (N=512) ; x1 = conv1(im0) -> SL1 (N=384)
    { JB b{}; b.add(SL[2], sda_wvb, SL[0], NB, 512, DM, DM, DM, sda_bv, 1.f, nullptr, nullptr, 0, 0);
              b.add(SL[3], w1c,     SL[1], NB, 384, DM, DM, DM, fda_b1, bnscale, bn1_g, bn1_b, 1, 0); launch(b); }
    // fused FDA tail (in place on SL1)
    fda_fused_k<<<dim3(NB), dim3(128), 0, stream>>>(SL[1], ca_w1, ca_w2, sac, sa_b, dec_w, dec_b, sigma);
    // J34: t1 = wv@wo^T -> SL4 (K=512) ; im1 = gelu((x4@wf^T+bf)*bn2) -> SL5 (K=384)
    { JB b{}; b.add(SL[0], sda_wob, SL[4], NB, DM, 512, 512, 512, sda_bo, 1.f, nullptr, nullptr, 0, 0);
              b.add(SL[1], fda_wfb, SL[5], NB, DM, 384, 384, 384, fda_bf, bnscale, bn2_g, bn2_b, 1, 0); launch(b); }

    // J5: QKV both directions (6 jobs)
    { JB b{};
      b.add(SL[4], dmi_wqb, SL[0], NB, DM, DM, DM, DM, dmi_bq, 1.f, nullptr, nullptr, 0, 0);
      b.add(SL[5], dmi_wkb, SL[1], NB, DM, DM, DM, DM, dmi_bk, 1.f, nullptr, nullptr, 0, 0);
      b.add(SL[5], dmi_wvb, SL[2], NB, DM, DM, DM, DM, dmi_bv, 1.f, nullptr, nullptr, 0, 1);
      b.add(SL[5], dmi_wqb, SL[3], NB, DM, DM, DM, DM, dmi_bq, 1.f, nullptr, nullptr, 0, 0);
      b.add(SL[4], dmi_wkb, SL[6], NB, DM, DM, DM, DM, dmi_bk, 1.f, nullptr, nullptr, 0, 0);
      b.add(SL[4], dmi_wvb, SL[7], NB, DM, DM, DM, DM, dmi_bv, 1.f, nullptr, nullptr, 0, 1);
      launch(b); }
    // J6: scores with fused exp + per-block partial row sums + 8x8 supertile swizzle
    { JB b{};
      b.add(SL[0], SL[1], SC1, NB, NB, DM, DM, DM, nullptr, iscale, nullptr, nullptr, 4, 0, part).sw = 1;
      b.add(SL[3], SL[6], SC2, NB, NB, DM, DM, DM, nullptr, iscale, nullptr, nullptr, 4, 0, part + 32 * NB).sw = 1;
      launch(b); }
    denom_k<<<dim3((2 * NB + 255) / 256), blk, 0, stream>>>(part, lbuf);
    // J7: PV split-K=2 x 2 dirs (4 jobs, 768 blocks) on unnormalized exp-scores
    { JB b{};
      b.add(SC1,        SL[2],        SL[0], NB, DM, 2048, NB, NB, nullptr, 1.f, nullptr, nullptr, 0, 0);
      b.add(SC1 + 2048, SL[2] + 2048, SL[1], NB, DM, 2048, NB, NB, nullptr, 1.f, nullptr, nullptr, 0, 0);
      b.add(SC2,        SL[7],        SL[3], NB, DM, 2048, NB, NB, nullptr, 1.f, nullptr, nullptr, 0, 0);
      b.add(SC2 + 2048, SL[7] + 2048, SL[6], NB, DM, 2048, NB, NB, nullptr, 1.f, nullptr, nullptr, 0, 0);
      launch(b); }
    // a1 = (SL0+SL1)/l1 -> SL4 ; a2 = (SL3+SL6)/l2 -> SL5
    reduce2_k<<<dim3((int)(SLOT / 2048)), blk, 0, stream>>>(SL[0], SL[1], SL[4], lbuf,
                                                           SL[3], SL[6], SL[5], lbuf + NB);
    // J8: gate hidden (relu)
    { JB b{}; b.add(SL[4], tg_w1b, SL[0], NB, DM, DM, DM, DM, tg_b1, 1.f, nullptr, nullptr, 3, 0);
              b.add(SL[5], ig_w1b, SL[1], NB, DM, DM, DM, DM, ig_b1, 1.f, nullptr, nullptr, 3, 0); launch(b); }
    // J9: gate out fused with combine + classifier partials (no gate materialization)
    { JB b{};
      Job& j1 = b.add(SL[0], tg_w2b, SL[3], NB, DM, DM, DM, DM, tg_b2, 1.f, nullptr, nullptr, 0, 0);
      j1.ca = SL[4]; j1.cs = t_scale; j1.cw = cls_w; j1.cp = clsp;
      Job& j2 = b.add(SL[1], ig_w2b, SL[6], NB, DM, DM, DM, DM, ig_b2, 1.f, nullptr, nullptr, 0, 0);
      j2.ca = SL[5]; j2.cs = i_scale; j2.cw = cls_w; j2.cp = clsp + (size_t)6 * NB * 3;
      launch(b); }
    cls_final_k<<<dim3((NB + 255) / 256), blk, 0, stream>>>(clsp, cls_b, out);
}

// Round 13
// 583.888 us; speedup vs baseline: 1.0657x; 1.0657x over previous
//
#include <hip/hip_runtime.h>
#include <hip/hip_bf16.h>
#include <math.h>

typedef __hip_bfloat16 bf16;
typedef __bf16 bf16x8 __attribute__((ext_vector_type(8)));
typedef float f32x4 __attribute__((ext_vector_type(4)));
typedef unsigned short u16;
typedef u16 u16x8 __attribute__((ext_vector_type(8)));

#define NB 4096          // batch rows
#define DM 768           // model dim

__device__ __forceinline__ float cvt(float x){ return x; }
__device__ __forceinline__ float cvt(bf16 x){ return __bfloat162float(x); }
__device__ __forceinline__ void stv(float* p, float v){ *p = v; }
__device__ __forceinline__ void stv(bf16* p, float v){ *p = __float2bfloat16(v); }

__device__ __forceinline__ float gelu_f(float x){
    return 0.5f * x * (1.0f + erff(x * 0.70710678118654752440f));
}
__device__ __forceinline__ float sigmoid_f(float x){
    return 1.0f / (1.0f + __expf(-x));
}

__device__ __forceinline__ void async_copy16(const void* g, void* l){
    __builtin_amdgcn_global_load_lds((const __attribute__((address_space(1))) void*)g,
                                     (__attribute__((address_space(3))) void*)l, 16, 0, 0);
}

// ---------------------------------------------------------------------------
// Flat multi-job MFMA GEMM (R7/R11 K-loop+epilogue -- proven optimum).
// LESSONS: R8 32KB two-pass epilogue REGRESSED; R10 atomic rowsum REGRESSED;
// R12 single-kernel cls branch REGRESSED via VGPR 80->96 on ALL dispatches
// (hence the CLSM template split); R12 8x8 supertile swizzle: FETCH unchanged,
// useless (score fetch is compulsory/cross-XCD, not L2-capacity limited).
// Per job: C = act((A @ Bm^T + b0) * alpha * gv + b1)
// act: 0 none, 1 gelu, 2 sigmoid, 3 relu, 4 exp (__expf; scores tiny -> no max).
// rs: per-block partial row sums -> rs[gx*M+row] (exactly-once, no atomics).
// CLSM=1 (separate instantiation): no C store; gate=sig((acc+b0)); partial
// logits cp[gx][row][3] from sig(gate) * ca[row,col] * cs[col] . cw[class,col]
// (double sigmoid per reference).
// A: (M,ldA) bf16 cols [0,K). Bm: (N,ldB) bf16 (B^T layout) cols [0,K).
// M%128==0, N%128==0, K%64==0. trans=1: store C^T into (N,M).
// ---------------------------------------------------------------------------
#define MAXJ 8
struct Job {
    const bf16* A; const bf16* B; bf16* C;
    const float* b0; const float* gv; const float* b1;
    float* rs;
    const bf16* ca; const float* cs; const float* cw; float* cp;
    int M, N, K, ldA, ldB, act, trans, blk0, nx;
    float alpha;
};
struct Jobs { Job j[MAXJ]; int nj; };

template<int CLSM>
__global__ __launch_bounds__(256) void mgemm_k(Jobs jb)
{
    int z = 0;
    #pragma unroll
    for (int i = 1; i < MAXJ; ++i)
        if (i < jb.nj && (int)blockIdx.x >= jb.j[i].blk0) z = i;
    const Job& J = jb.j[z];
    const bf16* __restrict__ A  = J.A;
    const bf16* __restrict__ Bm = J.B;
    bf16* __restrict__ C        = J.C;
    const int bx = (int)blockIdx.x - J.blk0;
    const int gx = bx % J.nx;
    const int gy = bx / J.nx;
    const int M = J.M, N = J.N, K = J.K, ldA = J.ldA, ldB = J.ldB;

    // staging: A = smem[0 .. 8191] (128x64), B = smem[8192 .. 16383]
    // epilogue: 128x136 bf16 tile = 17408 elems
    __shared__ __align__(16) bf16 smem[17408];
    const int tid  = threadIdx.x;
    const int wave = tid >> 6;
    const int lane = tid & 63;
    const int row0 = gy * 128;
    const int col0 = gx * 128;
    const int wrow = (wave & 1) * 64;
    const int wcol = (wave >> 1) * 64;
    const int fl   = lane & 15;
    const int q    = lane >> 4;

    // staging: per instr a wave stages 8 rows x 64 cols (1 KiB).
    // phys chunk (lane&7) at row r holds logical chunk (lane&7)^(r&7).
    const int sr8 = lane >> 3;
    const int sc8 = (((lane & 7) ^ sr8)) * 8;
    const bf16* pA = A  + (size_t)(row0 + wave * 32 + sr8) * ldA + sc8;
    const bf16* pB = Bm + (size_t)(col0 + wave * 32 + sr8) * ldB + sc8;
    bf16* ldsA = &smem[(wave * 32) * 64];
    bf16* ldsB = &smem[8192 + (wave * 32) * 64];

    f32x4 acc[4][4] = {};
    for (int k0 = 0; k0 < K; k0 += 64){
        #pragma unroll
        for (int i = 0; i < 4; ++i){
            async_copy16(pA + (size_t)(i * 8) * ldA, ldsA + i * 512);
            async_copy16(pB + (size_t)(i * 8) * ldB, ldsB + i * 512);
        }
        pA += 64; pB += 64;
        __syncthreads();
        #pragma unroll
        for (int ks = 0; ks < 2; ++ks){
            bf16x8 af[4], bfv[4];
            #pragma unroll
            for (int i = 0; i < 4; ++i){
                const int ra = wrow + i * 16 + fl;
                const int rb = wcol + i * 16 + fl;
                const int ca2 = ((ks * 4 + q) ^ (ra & 7)) * 8;
                const int cb2 = ((ks * 4 + q) ^ (rb & 7)) * 8;
                af[i]  = *(const bf16x8*)&smem[ra * 64 + ca2];
                bfv[i] = *(const bf16x8*)&smem[8192 + rb * 64 + cb2];
            }
            #pragma unroll
            for (int mi = 0; mi < 4; ++mi)
                #pragma unroll
                for (int ni = 0; ni < 4; ++ni)
                    acc[mi][ni] = __builtin_amdgcn_mfma_f32_16x16x32_bf16(af[mi], bfv[ni], acc[mi][ni], 0, 0, 0);
        }
        __syncthreads();
    }

    if constexpr (CLSM == 0){
        // standard epilogue: C/D layout col = lane&15, row = q*4 + reg.
        // stage to LDS (padded ld=136), block-wide 256 B coalesced stores.
        constexpr int ELD = 136;
        #pragma unroll
        for (int ni = 0; ni < 4; ++ni){
            const int col = col0 + wcol + ni * 16 + fl;
            const float b0 = J.b0 ? J.b0[col] : 0.f;
            const float gm = (J.gv ? J.gv[col] : 1.f) * J.alpha;
            const float b1 = J.b1 ? J.b1[col] : 0.f;
            const int lcol = wcol + ni * 16 + fl;
            #pragma unroll
            for (int mi = 0; mi < 4; ++mi){
                const int lrow = wrow + mi * 16 + q * 4;
                #pragma unroll
                for (int r = 0; r < 4; ++r){
                    float v = (acc[mi][ni][r] + b0) * gm + b1;
                    if      (J.act == 1) v = gelu_f(v);
                    else if (J.act == 2) v = sigmoid_f(v);
                    else if (J.act == 3) v = fmaxf(v, 0.f);
                    else if (J.act == 4) v = __expf(v);
                    if (J.trans) smem[(size_t)lcol * ELD + lrow + r] = __float2bfloat16(v);
                    else         smem[(size_t)(lrow + r) * ELD + lcol] = __float2bfloat16(v);
                }
            }
        }
        __syncthreads();
        const int erow = tid >> 4;
        const int ecol = (tid & 15) * 8;
        #pragma unroll
        for (int p = 0; p < 8; ++p){
            const int row = p * 16 + erow;
            const u16x8 uv = *(const u16x8*)&smem[row * ELD + ecol];
            if (J.trans) *(u16x8*)&C[(size_t)(col0 + row) * M + row0 + ecol] = uv;
            else         *(u16x8*)&C[(size_t)(row0 + row) * N + col0 + ecol] = uv;
            if (J.rs){
                float s = 0.f;
                #pragma unroll
                for (int j = 0; j < 8; ++j) s += __uint_as_float((unsigned)uv[j] << 16);
                s += __shfl_down(s, 8, 16);
                s += __shfl_down(s, 4, 16);
                s += __shfl_down(s, 2, 16);
                s += __shfl_down(s, 1, 16);
                if ((tid & 15) == 0) J.rs[(size_t)gx * M + row0 + row] = s;
            }
        }
    } else {
        // cls-fusion epilogue (separate instantiation -- keeps standard path at
        // low VGPR). Double sigmoid per reference: gate = sig(logits);
        // contribution = sig(gate) * a * scale, reduced against cls_w.
        float* sp = (float*)smem;
        const int colhalf = wave >> 1;
        #pragma unroll
        for (int mi = 0; mi < 4; ++mi){
            #pragma unroll
            for (int r = 0; r < 4; ++r){
                const int lrow = wrow + mi * 16 + q * 4 + r;
                const int grow = row0 + lrow;
                float s0 = 0.f, s1 = 0.f, s2 = 0.f;
                #pragma unroll
                for (int ni = 0; ni < 4; ++ni){
                    const int col = col0 + wcol + ni * 16 + fl;
                    const float b0 = J.b0 ? J.b0[col] : 0.f;
                    const float gate = sigmoid_f((acc[mi][ni][r] + b0) * J.alpha);
                    const float t = sigmoid_f(gate) * cvt(J.ca[(size_t)grow * DM + col]) * J.cs[col];
                    s0 = fmaf(t, J.cw[col],          s0);
                    s1 = fmaf(t, J.cw[DM + col],     s1);
                    s2 = fmaf(t, J.cw[2 * DM + col], s2);
                }
                #pragma unroll
                for (int m2 = 1; m2 < 16; m2 <<= 1){
                    s0 += __shfl_xor(s0, m2, 64);
                    s1 += __shfl_xor(s1, m2, 64);
                    s2 += __shfl_xor(s2, m2, 64);
                }
                if (fl == 0){
                    sp[colhalf * 384 + lrow * 3 + 0] = s0;
                    sp[colhalf * 384 + lrow * 3 + 1] = s1;
                    sp[colhalf * 384 + lrow * 3 + 2] = s2;
                }
            }
        }
        __syncthreads();
        if (tid < 128){
            float* dst = J.cp + ((size_t)gx * NB + row0 + tid) * 3;
            dst[0] = sp[tid * 3 + 0] + sp[384 + tid * 3 + 0];
            dst[1] = sp[tid * 3 + 1] + sp[384 + tid * 3 + 1];
            dst[2] = sp[tid * 3 + 2] + sp[384 + tid * 3 + 2];
        }
    }
}

// Final: logits[row] = sum over 2 dirs x 6 col-chunks of partials + bias; softmax(3)
__global__ __launch_bounds__(256) void cls_final_k(
    const float* __restrict__ part, const float* __restrict__ bias, float* __restrict__ out)
{
    const int row = blockIdx.x * 256 + threadIdx.x;
    if (row >= NB) return;
    float l0 = bias[0], l1 = bias[1], l2 = bias[2];
    #pragma unroll
    for (int s = 0; s < 12; ++s){
        const float* p = part + ((size_t)s * NB + row) * 3;
        l0 += p[0]; l1 += p[1]; l2 += p[2];
    }
    const float mx = fmaxf(l0, fmaxf(l1, l2));
    const float e0 = __expf(l0 - mx), e1 = __expf(l1 - mx), e2 = __expf(l2 - mx);
    const float inv = 1.f / (e0 + e1 + e2);
    out[(size_t)row * 3 + 0] = e0 * inv;
    out[(size_t)row * 3 + 1] = e1 * inv;
    out[(size_t)row * 3 + 2] = e2 * inv;
}

// Reduce 32 per-chunk partials per row into the softmax denominator.
__global__ __launch_bounds__(256) void denom_k(const float* __restrict__ part, float* __restrict__ l)
{
    const int t = blockIdx.x * 256 + threadIdx.x;
    if (t >= 2 * NB) return;
    const int dir = t >> 12, row = t & (NB - 1);
    const float* p = part + (size_t)dir * 32 * NB + row;
    float s = 0.f;
    #pragma unroll
    for (int c = 0; c < 32; ++c) s += p[(size_t)c * NB];
    l[t] = s;
}

// Batched fp32 -> bf16 conversion; last y-slice does the conv center-tap extraction
#define NCVT 14
struct CvtDesc {
    const float* s[NCVT]; bf16* d[NCVT]; int n[NCVT];
    const float* w1; const float* saw; bf16* w1c; float* sac;
};
__global__ __launch_bounds__(256) void cvt_k(CvtDesc cd)
{
    const int e = blockIdx.y;
    if (e == NCVT){
        const int idx = blockIdx.x * 256 + threadIdx.x;
        if (idx < 384 * 768){
            const int oc = idx / 768, ic = idx % 768;
            cd.w1c[idx] = __float2bfloat16(cd.w1[(size_t)oc * 6912 + (size_t)ic * 9 + 4]);
        }
        if (idx < 384) cd.sac[idx] = cd.saw[(size_t)idx * 49 + 24];
        return;
    }
    const int base = (blockIdx.x * 256 + threadIdx.x) * 4;
    if (base >= cd.n[e]) return;
    const float4 v = *(const float4*)(cd.s[e] + base);
    union { bf16 h[4]; unsigned long long u; } o;
    o.h[0] = __float2bfloat16(v.x);
    o.h[1] = __float2bfloat16(v.y);
    o.h[2] = __float2bfloat16(v.z);
    o.h[3] = __float2bfloat16(v.w);
    *(unsigned long long*)(cd.d[e] + base) = o.u;
}

// Fused FDA tail: ca1 -> ca2 -> x2 -> sa -> x3 -> dec -> x4, in place
__global__ __launch_bounds__(128) void fda_fused_k(
    bf16* __restrict__ x, const float* __restrict__ wc1, const float* __restrict__ wc2,
    const float* __restrict__ sac, const float* __restrict__ sab,
    const float* __restrict__ decw, const float* __restrict__ decb,
    const float* __restrict__ sigma)
{
    __shared__ float xs[384];
    __shared__ float ca1s[24];
    __shared__ float red[128];
    const int b = blockIdx.x;
    const int tid = threadIdx.x;
    bf16* xr = x + (size_t)b * 384;
    #pragma unroll
    for (int i = 0; i < 3; ++i) xs[tid + i * 128] = cvt(xr[tid + i * 128]);
    __syncthreads();
    if (tid < 96){
        const int o = tid >> 2, sub = tid & 3;
        const float* w = wc1 + (size_t)o * 384 + sub * 96;
        float p = 0.f;
        #pragma unroll 8
        for (int k = 0; k < 96; ++k) p = fmaf(xs[sub * 96 + k], w[k], p);
        p += __shfl_down(p, 1, 64);
        p += __shfl_down(p, 2, 64);
        if (sub == 0) ca1s[o] = gelu_f(p);
    }
    __syncthreads();
    float x2[3];
    float p = 0.f;
    #pragma unroll
    for (int i = 0; i < 3; ++i){
        const int c = tid + i * 128;
        float s = 0.f;
        const float* w = wc2 + (size_t)c * 24;
        #pragma unroll
        for (int k = 0; k < 24; ++k) s = fmaf(ca1s[k], w[k], s);
        const float v = xs[c] * sigmoid_f(s);
        x2[i] = v;
        p += v * sac[c];
    }
    red[tid] = p; __syncthreads();
    for (int s = 64; s > 0; s >>= 1){ if (tid < s) red[tid] += red[tid + s]; __syncthreads(); }
    const float sa = sigmoid_f(red[0] + sab[0]);
    __syncthreads();
    float qq = 0.f;
    #pragma unroll
    for (int i = 0; i < 3; ++i){
        const int c = tid + i * 128;
        x2[i] *= sa;
        qq += x2[i] * decw[c];
    }
    red[tid] = qq; __syncthreads();
    for (int s = 64; s > 0; s >>= 1){ if (tid < s) red[tid] += red[tid + s]; __syncthreads(); }
    const float xg = gelu_f(red[0] + decb[0]);
    #pragma unroll
    for (int i = 0; i < 3; ++i){
        const int c = tid + i * 128;
        const float sg = sigma[c];
        stv(&xr[c], x2[i] + sg * (x2[i] - xg));
    }
}

// o1 = (a+b)/l1[row] ; o2 = (c+d)/l2[row]  (split-K reduce + softmax denom)
__global__ __launch_bounds__(256) void reduce2_k(
    const bf16* __restrict__ a, const bf16* __restrict__ b, bf16* __restrict__ o1,
    const float* __restrict__ l1,
    const bf16* __restrict__ c, const bf16* __restrict__ d, bf16* __restrict__ o2,
    const float* __restrict__ l2)
{
    const size_t i = ((size_t)blockIdx.x * 256 + threadIdx.x) * 8;
    if (i >= (size_t)NB * DM) return;
    const int row = (int)(i / DM);
    const float inv1 = 1.0f / l1[row];
    const float inv2 = 1.0f / l2[row];
    u16x8 ua = *(const u16x8*)((const u16*)a + i);
    u16x8 ub = *(const u16x8*)((const u16*)b + i);
    u16x8 uc = *(const u16x8*)((const u16*)c + i);
    u16x8 ud = *(const u16x8*)((const u16*)d + i);
    u16x8 r1, r2;
    #pragma unroll
    for (int j = 0; j < 8; ++j){
        const float s1 = (__uint_as_float((unsigned)ua[j] << 16) + __uint_as_float((unsigned)ub[j] << 16)) * inv1;
        const float s2 = (__uint_as_float((unsigned)uc[j] << 16) + __uint_as_float((unsigned)ud[j] << 16)) * inv2;
        r1[j] = __bfloat16_as_ushort(__float2bfloat16(s1));
        r2[j] = __bfloat16_as_ushort(__float2bfloat16(s2));
    }
    *(u16x8*)((u16*)o1 + i) = r1;
    *(u16x8*)((u16*)o2 + i) = r2;
}

extern "C" void kernel_launch(void* const* d_in, const int* in_sizes, int n_in,
                              void* d_out, int out_size, void* d_ws, size_t ws_size,
                              hipStream_t stream)
{
    const float* text   = (const float*)d_in[0];
    const float* image  = (const float*)d_in[1];
    const float* tl_w   = (const float*)d_in[2];
    const float* tl_b   = (const float*)d_in[3];
    const float* il_w   = (const float*)d_in[4];
    const float* il_b   = (const float*)d_in[5];
    const float* sda_wv = (const float*)d_in[10];
    const float* sda_bv = (const float*)d_in[11];
    const float* sda_wo = (const float*)d_in[12];
    const float* sda_bo = (const float*)d_in[13];
    const float* fda_w1 = (const float*)d_in[14];
    const float* fda_b1 = (const float*)d_in[15];
    const float* bn1_g  = (const float*)d_in[16];
    const float* bn1_b  = (const float*)d_in[17];
    const float* ca_w1  = (const float*)d_in[18];
    const float* ca_w2  = (const float*)d_in[19];
    const float* sa_w   = (const float*)d_in[20];
    const float* sa_b   = (const float*)d_in[21];
    const float* dec_w  = (const float*)d_in[22];
    const float* dec_b  = (const float*)d_in[23];
    const float* sigma  = (const float*)d_in[24];
    const float* fda_wf = (const float*)d_in[25];
    const float* fda_bf = (const float*)d_in[26];
    const float* bn2_g  = (const float*)d_in[27];
    const float* bn2_b  = (const float*)d_in[28];
    const float* dmi_wq = (const float*)d_in[29];
    const float* dmi_bq = (const float*)d_in[30];
    const float* dmi_wk = (const float*)d_in[31];
    const float* dmi_bk = (const float*)d_in[32];
    const float* dmi_wv = (const float*)d_in[33];
    const float* dmi_bv = (const float*)d_in[34];
    const float* tg_w1  = (const float*)d_in[35];
    const float* tg_b1  = (const float*)d_in[36];
    const float* tg_w2  = (const float*)d_in[37];
    const float* tg_b2  = (const float*)d_in[38];
    const float* ig_w1  = (const float*)d_in[39];
    const float* ig_b1  = (const float*)d_in[40];
    const float* ig_w2  = (const float*)d_in[41];
    const float* ig_b2  = (const float*)d_in[42];
    const float* t_scale= (const float*)d_in[43];
    const float* i_scale= (const float*)d_in[44];
    const float* cls_w  = (const float*)d_in[45];
    const float* cls_b  = (const float*)d_in[46];
    float* out = (float*)d_out;

    // ---- workspace (~130 MB) ----
    char* base = (char*)d_ws;
    auto alloc = [&](size_t bytes){ void* p = (void*)base; base += (bytes + 255) & ~(size_t)255; return p; };
    const size_t SLOT = (size_t)NB * DM;
    const size_t W768 = (size_t)768 * 768;
    bf16* tl_wb   = (bf16*)alloc(W768 * 2);
    bf16* il_wb   = (bf16*)alloc(W768 * 2);
    bf16* sda_wvb = (bf16*)alloc((size_t)512 * 768 * 2);
    bf16* sda_wob = (bf16*)alloc((size_t)768 * 512 * 2);
    bf16* fda_wfb = (bf16*)alloc((size_t)768 * 384 * 2);
    bf16* dmi_wqb = (bf16*)alloc(W768 * 2);
    bf16* dmi_wkb = (bf16*)alloc(W768 * 2);
    bf16* dmi_wvb = (bf16*)alloc(W768 * 2);
    bf16* tg_w1b  = (bf16*)alloc(W768 * 2);
    bf16* tg_w2b  = (bf16*)alloc(W768 * 2);
    bf16* ig_w1b  = (bf16*)alloc(W768 * 2);
    bf16* ig_w2b  = (bf16*)alloc(W768 * 2);
    bf16* w1c     = (bf16*)alloc((size_t)384 * 768 * 2);
    float* sac    = (float*)alloc(1536 * 4);
    float* lbuf   = (float*)alloc(2 * NB * 4);               // softmax denominators [2][NB]
    float* part   = (float*)alloc((size_t)2 * 32 * NB * 4);  // score rowsum partials, 1 MB
    float* clsp   = (float*)alloc((size_t)2 * 6 * NB * 3 * 4); // cls logit partials, 590 KB
    bf16* SL[8];
    for (int i = 0; i < 8; ++i) SL[i] = (bf16*)alloc(SLOT * 2);
    bf16* SC1 = (bf16*)alloc((size_t)NB * NB * 2);
    bf16* SC2 = (bf16*)alloc((size_t)NB * NB * 2);

    const float bnscale = 1.0f / sqrtf(1.0f + 1e-5f);
    const float iscale  = 1.0f / sqrtf(768.0f);
    const dim3 blk(256);

    struct JB {
        Jobs jb; int blocks;
        Job& add(const bf16* A, const bf16* B, bf16* C, int M, int N, int K, int ldA, int ldB,
                 const float* b0, float al, const float* gv, const float* b1, int act, int trans,
                 float* rs = nullptr){
            Job& j = jb.j[jb.nj++];
            j = Job{};
            j.A=A; j.B=B; j.C=C; j.b0=b0; j.gv=gv; j.b1=b1; j.rs=rs;
            j.M=M; j.N=N; j.K=K; j.ldA=ldA; j.ldB=ldB; j.act=act; j.trans=trans;
            j.alpha=al; j.blk0=blocks; j.nx=N/128;
            blocks += (N/128)*(M/128);
            return j;
        }
    };
    auto launch  = [&](JB& b){ mgemm_k<0><<<dim3(b.blocks), blk, 0, stream>>>(b.jb); };
    auto launchC = [&](JB& b){ mgemm_k<1><<<dim3(b.blocks), blk, 0, stream>>>(b.jb); };

    // fp32 -> bf16 staging (+ fused center-tap extraction in y-slice NCVT)
    CvtDesc cd;
    const float* srcs[NCVT] = {text, image, tl_w, il_w, sda_wv, sda_wo, fda_wf,
                               dmi_wq, dmi_wk, dmi_wv, tg_w1, tg_w2, ig_w1, ig_w2};
    bf16* dsts[NCVT] = {SL[0], SL[1], tl_wb, il_wb, sda_wvb, sda_wob, fda_wfb,
                        dmi_wqb, dmi_wkb, dmi_wvb, tg_w1b, tg_w2b, ig_w1b, ig_w2b};
    int   lens[NCVT] = {(int)SLOT, (int)SLOT, (int)W768, (int)W768, 512*768, 768*512, 768*384,
                        (int)W768, (int)W768, (int)W768, (int)W768, (int)W768, (int)W768, (int)W768};
    for (int i = 0; i < NCVT; ++i){ cd.s[i] = srcs[i]; cd.d[i] = dsts[i]; cd.n[i] = lens[i]; }
    cd.w1 = fda_w1; cd.saw = sa_w; cd.w1c = w1c; cd.sac = sac;
    cvt_k<<<dim3((int)(SLOT / 1024), NCVT + 1), blk, 0, stream>>>(cd);

    // J1: t0 = gelu(text@tl^T) -> SL2 ; im0 = gelu(image@il^T) -> SL3
    { JB b{}; b.add(SL[0], tl_wb, SL[2], NB, DM, DM, DM, DM, tl_b, 1.f, nullptr, nullptr, 1, 0);
              b.add(SL[1], il_wb, SL[3], NB, DM, DM, DM, DM, il_b, 1.f, nullptr, nullptr, 1, 0); launch(b); }
    // J2: wv = t0@wv^T -> SL0 (N=512) ; x1 = conv1(im0) -> SL1 (N=384)
    { JB b{}; b.add(SL[2], sda_wvb, SL[0], NB, 512, DM, DM, DM, sda_bv, 1.f, nullptr, nullptr, 0, 0);
              b.add(SL[3], w1c,     SL[1], NB, 384, DM, DM, DM, fda_b1, bnscale, bn1_g, bn1_b, 1, 0); launch(b); }
    // fused FDA tail (in place on SL1)
    fda_fused_k<<<dim3(NB), dim3(128), 0, stream>>>(SL[1], ca_w1, ca_w2, sac, sa_b, dec_w, dec_b, sigma);
    // J34: t1 = wv@wo^T -> SL4 (K=512) ; im1 = gelu((x4@wf^T+bf)*bn2) -> SL5 (K=384)
    { JB b{}; b.add(SL[0], sda_wob, SL[4], NB, DM, 512, 512, 512, sda_bo, 1.f, nullptr, nullptr, 0, 0);
              b.add(SL[1], fda_wfb, SL[5], NB, DM, 384, 384, 384, fda_bf, bnscale, bn2_g, bn2_b, 1, 0); launch(b); }

    // J5: QKV both directions (6 jobs)
    { JB b{};
      b.add(SL[4], dmi_wqb, SL[0], NB, DM, DM, DM, DM, dmi_bq, 1.f, nullptr, nullptr, 0, 0);
      b.add(SL[5], dmi_wkb, SL[1], NB, DM, DM, DM, DM, dmi_bk, 1.f, nullptr, nullptr, 0, 0);
      b.add(SL[5], dmi_wvb, SL[2], NB, DM, DM, DM, DM, dmi_bv, 1.f, nullptr, nullptr, 0, 1);
      b.add(SL[5], dmi_wqb, SL[3], NB, DM, DM, DM, DM, dmi_bq, 1.f, nullptr, nullptr, 0, 0);
      b.add(SL[4], dmi_wkb, SL[6], NB, DM, DM, DM, DM, dmi_bk, 1.f, nullptr, nullptr, 0, 0);
      b.add(SL[4], dmi_wvb, SL[7], NB, DM, DM, DM, DM, dmi_bv, 1.f, nullptr, nullptr, 0, 1);
      launch(b); }
    // J6: scores with fused exp + per-block partial row sums (no atomics, no swizzle)
    { JB b{}; b.add(SL[0], SL[1], SC1, NB, NB, DM, DM, DM, nullptr, iscale, nullptr, nullptr, 4, 0, part);
              b.add(SL[3], SL[6], SC2, NB, NB, DM, DM, DM, nullptr, iscale, nullptr, nullptr, 4, 0, part + 32 * NB); launch(b); }
    denom_k<<<dim3((2 * NB + 255) / 256), blk, 0, stream>>>(part, lbuf);
    // J7: PV split-K=2 x 2 dirs (4 jobs, 768 blocks) on unnormalized exp-scores
    { JB b{};
      b.add(SC1,        SL[2],        SL[0], NB, DM, 2048, NB, NB, nullptr, 1.f, nullptr, nullptr, 0, 0);
      b.add(SC1 + 2048, SL[2] + 2048, SL[1], NB, DM, 2048, NB, NB, nullptr, 1.f, nullptr, nullptr, 0, 0);
      b.add(SC2,        SL[7],        SL[3], NB, DM, 2048, NB, NB, nullptr, 1.f, nullptr, nullptr, 0, 0);
      b.add(SC2 + 2048, SL[7] + 2048, SL[6], NB, DM, 2048, NB, NB, nullptr, 1.f, nullptr, nullptr, 0, 0);
      launch(b); }
    // a1 = (SL0+SL1)/l1 -> SL4 ; a2 = (SL3+SL6)/l2 -> SL5
    reduce2_k<<<dim3((int)(SLOT / 2048)), blk, 0, stream>>>(SL[0], SL[1], SL[4], lbuf,
                                                           SL[3], SL[6], SL[5], lbuf + NB);
    // J8: gate hidden (relu)
    { JB b{}; b.add(SL[4], tg_w1b, SL[0], NB, DM, DM, DM, DM, tg_b1, 1.f, nullptr, nullptr, 3, 0);
              b.add(SL[5], ig_w1b, SL[1], NB, DM, DM, DM, DM, ig_b1, 1.f, nullptr, nullptr, 3, 0); launch(b); }
    // J9 (CLS instantiation): gate out + double-sigmoid combine + classifier partials
    { JB b{};
      Job& j1 = b.add(SL[0], tg_w2b, nullptr, NB, DM, DM, DM, DM, tg_b2, 1.f, nullptr, nullptr, 0, 0);
      j1.ca = SL[4]; j1.cs = t_scale; j1.cw = cls_w; j1.cp = clsp;
      Job& j2 = b.add(SL[1], ig_w2b, nullptr, NB, DM, DM, DM, DM, ig_b2, 1.f, nullptr, nullptr, 0, 0);
      j2.ca = SL[5]; j2.cs = i_scale; j2.cw = cls_w; j2.cp = clsp + (size_t)6 * NB * 3;
      launchC(b); }
    cls_final_k<<<dim3((NB + 255) / 256), blk, 0, stream>>>(clsp, cls_b, out);
}